// Round 1
// baseline (343.534 us; speedup 1.0000x reference)
//
#include <hip/hip_runtime.h>
#include <cstdint>
#include <cstddef>

#define THETA 1.2f
#define XI 0.3f
#define BDIM 8192
#define DDIM 512
#define NT_TILES 8256      // 128*129/2 upper-triangle 64x64 wave-tiles
#define NBLK 2064          // 4 wave-tiles per 256-thread block
// upper-triangle-with-diagonal pair count: B*(B+1)/2
#define NPAIRS_UP (((double)BDIM * (double)(BDIM + 1)) * 0.5)

typedef float f32x4 __attribute__((ext_vector_type(4)));
typedef int i32x8 __attribute__((ext_vector_type(8)));

// Kernel 1: per-row L2 normalize fp32 -> fp8 e4m3, coalesced; sq[row]=||n||^2; zero counter.
__global__ __launch_bounds__(256) void normalize_rows(
    const float* __restrict__ x, unsigned char* __restrict__ nf8,
    float* __restrict__ sq, unsigned int* __restrict__ counter)
{
    if (blockIdx.x == 0 && threadIdx.x == 0) { *counter = 0u; }
    int row = blockIdx.x * 4 + (threadIdx.x >> 6);
    int l = threadIdx.x & 63;
    const float4* xr = (const float4*)(x + (size_t)row * DDIM);
    float4 f0 = xr[l];
    float4 f1 = xr[l + 64];
    float s = f0.x*f0.x + f0.y*f0.y + f0.z*f0.z + f0.w*f0.w
            + f1.x*f1.x + f1.y*f1.y + f1.z*f1.z + f1.w*f1.w;
    #pragma unroll
    for (int m = 1; m < 64; m <<= 1) s += __shfl_xor(s, m);
    float rn = rsqrtf(s);
    int pk0 = __builtin_amdgcn_cvt_pk_fp8_f32(f0.x * rn, f0.y * rn, 0, false);
    pk0     = __builtin_amdgcn_cvt_pk_fp8_f32(f0.z * rn, f0.w * rn, pk0, true);
    int pk1 = __builtin_amdgcn_cvt_pk_fp8_f32(f1.x * rn, f1.y * rn, 0, false);
    pk1     = __builtin_amdgcn_cvt_pk_fp8_f32(f1.z * rn, f1.w * rn, pk1, true);
    int* rowp = (int*)(nf8 + (size_t)row * DDIM);
    rowp[l] = pk0;
    rowp[l + 64] = pk1;
    if (l == 0) sq[row] = s * rn * rn;
}

// Kernel 2: one 64x64 output tile PER WAVE, fully independent. No LDS staging,
// no barriers in the compute path. Operands read straight from global (nf8 is
// 4 MB -> L2-resident per XCD; the 4 waves of a block walk consecutive tiles
// of the same B panel so L1 catches most B re-reads). 8256 uniform wave-tiles
// in 2064 blocks; 3 waves/SIMD via launch bounds for latency hiding.
__global__ __launch_bounds__(256, 3) void gram_hinge(
    const unsigned char* __restrict__ nf8, const float* __restrict__ sq,
    const int* __restrict__ y, double* __restrict__ part,
    unsigned int* __restrict__ counter, float* __restrict__ out)
{
    __shared__ float wpart[4];
    __shared__ double dpart[4];
    __shared__ int is_last;

    int tid = threadIdx.x;
    int w = tid >> 6, l = tid & 63;
    int lr = l & 15, q = l >> 4;

    // ---- per-wave tile decode: u = tj*(tj+1)/2 + ti, ti<=tj (row-tile ti, col-tile tj)
    int u = blockIdx.x * 4 + w;
    int tj = (int)((sqrtf(8.0f * (float)u + 1.0f) - 1.0f) * 0.5f);
    while ((tj + 1) * (tj + 2) / 2 <= u) ++tj;
    while (tj * (tj + 1) / 2 > u) --tj;
    int ti = u - tj * (tj + 1) / 2;

    // per-lane operand base pointers: row = tile*64 + frag*16 + lr, 32 B at k-chunk q*32
    const unsigned char* Ab = nf8 + ((size_t)(ti * 64 + lr)) * DDIM + q * 32;
    const unsigned char* Bb = nf8 + ((size_t)(tj * 64 + lr)) * DDIM + q * 32;

    f32x4 accv[4][4] = {};

    #pragma unroll
    for (int it = 0; it < 4; ++it) {
        i32x8 af[4], bf[4];
        #pragma unroll
        for (int mi = 0; mi < 4; ++mi)
            af[mi] = *(const i32x8*)(Ab + (size_t)mi * 16 * DDIM + it * 128);
        #pragma unroll
        for (int ni = 0; ni < 4; ++ni)
            bf[ni] = *(const i32x8*)(Bb + (size_t)ni * 16 * DDIM + it * 128);
        #pragma unroll
        for (int mi = 0; mi < 4; ++mi)
            #pragma unroll
            for (int ni = 0; ni < 4; ++ni)
                accv[mi][ni] = __builtin_amdgcn_mfma_scale_f32_16x16x128_f8f6f4(
                    af[mi], bf[ni], accv[mi][ni],
                    0, 0, 0, 0x7F7F7F7F, 0, 0x7F7F7F7F);
    }

    // ---- Epilogue (C/D layout: col=lane&15 -> j, row=q*4+reg -> i) ----
    float acc0 = 0.f, acc1 = 0.f, acc2 = 0.f, acc3 = 0.f;
    int jb = tj * 64 + lr;
    float sqj[4]; int yj[4];
    #pragma unroll
    for (int ni = 0; ni < 4; ++ni) {
        sqj[ni] = sq[jb + ni * 16];
        yj[ni]  = y[jb + ni * 16];
    }
    if (ti != tj) {
        // strictly above diagonal: every element counts, no index test
        #pragma unroll
        for (int mi = 0; mi < 4; ++mi) {
            #pragma unroll
            for (int r = 0; r < 4; ++r) {
                int ia = ti * 64 + mi * 16 + q * 4 + r;
                float ci = THETA - sq[ia];
                int yi = y[ia];
                float h0 = fmaxf(fmaf(2.f, accv[mi][0][r], ci - sqj[0]), 0.f);
                acc0 += (yi == yj[0]) ? h0 : -h0;
                float h1 = fmaxf(fmaf(2.f, accv[mi][1][r], ci - sqj[1]), 0.f);
                acc1 += (yi == yj[1]) ? h1 : -h1;
                float h2 = fmaxf(fmaf(2.f, accv[mi][2][r], ci - sqj[2]), 0.f);
                acc2 += (yi == yj[2]) ? h2 : -h2;
                float h3 = fmaxf(fmaf(2.f, accv[mi][3][r], ci - sqj[3]), 0.f);
                acc3 += (yi == yj[3]) ? h3 : -h3;
            }
        }
    } else {
        // diagonal tile: count only local col >= local row
        int cl0 = lr;
        #pragma unroll
        for (int mi = 0; mi < 4; ++mi) {
            #pragma unroll
            for (int r = 0; r < 4; ++r) {
                int rl_ = mi * 16 + q * 4 + r;
                int ia = ti * 64 + rl_;
                float ci = THETA - sq[ia];
                int yi = y[ia];
                #pragma unroll
                for (int ni = 0; ni < 4; ++ni) {
                    float h = fmaxf(fmaf(2.f, accv[mi][ni][r], ci - sqj[ni]), 0.f);
                    float sh = (yi == yj[ni]) ? h : -h;
                    if (cl0 + ni * 16 >= rl_) acc0 += sh;
                }
            }
        }
    }

    float local = (acc0 + acc1) + (acc2 + acc3);
    #pragma unroll
    for (int off = 32; off > 0; off >>= 1) local += __shfl_down(local, off);
    if (l == 0) wpart[w] = local;
    __syncthreads();
    if (tid == 0) {
        double ssum = (double)wpart[0] + (double)wpart[1]
                    + (double)wpart[2] + (double)wpart[3];
        __hip_atomic_store(&part[blockIdx.x], ssum, __ATOMIC_RELEASE, __HIP_MEMORY_SCOPE_AGENT);
        unsigned int ticket = __hip_atomic_fetch_add(
            counter, 1u, __ATOMIC_ACQ_REL, __HIP_MEMORY_SCOPE_AGENT);
        is_last = (ticket == NBLK - 1) ? 1 : 0;
    }
    __syncthreads();
    if (is_last) {
        double s = 0.0;
        for (int i = tid; i < NBLK; i += 256)
            s += __hip_atomic_load(&part[i], __ATOMIC_ACQUIRE, __HIP_MEMORY_SCOPE_AGENT);
        #pragma unroll
        for (int off = 32; off > 0; off >>= 1) s += __shfl_down(s, off);
        if (l == 0) dpart[w] = s;
        __syncthreads();
        if (tid == 0) {
            // add the analytically-known XI term: XI * #upper-tri pairs
            double total = (dpart[0] + dpart[1] + dpart[2] + dpart[3])
                         + (double)XI * NPAIRS_UP;
            const double m = 1.0 / ((double)BDIM * (double)BDIM - (double)BDIM);
            out[0] = (float)(total * m);
        }
    }
}

extern "C" void kernel_launch(void* const* d_in, const int* in_sizes, int n_in,
                              void* d_out, int out_size, void* d_ws, size_t ws_size,
                              hipStream_t stream) {
    const float* x = (const float*)d_in[0];
    const int* y = (const int*)d_in[1];
    float* out = (float*)d_out;

    unsigned char* nf8 = (unsigned char*)d_ws;                          // 4 MB fp8
    char* p = (char*)d_ws + (size_t)BDIM * DDIM;
    float* sq = (float*)p;                                              // 32 KB
    unsigned int* counter = (unsigned int*)(p + (size_t)BDIM * 4);
    double* part = (double*)(p + (size_t)BDIM * 4 + 64);                // NBLK doubles

    normalize_rows<<<BDIM / 4, 256, 0, stream>>>(x, nf8, sq, counter);
    gram_hinge<<<NBLK, 256, 0, stream>>>(nf8, sq, y, part, counter, out);
}

// Round 2
// 181.287 us; speedup vs baseline: 1.8950x; 1.8950x over previous
//
#include <hip/hip_runtime.h>
#include <cstdint>
#include <cstddef>

#define THETA 1.2f
#define XI 0.3f
#define BDIM 8192
#define DDIM 512
#define NT_TILES 8256      // 128*129/2 upper-triangle 64x64 wave-tiles
#define NBLK 2064          // 4 wave-tiles per 256-thread block
// upper-triangle-with-diagonal pair count: B*(B+1)/2
#define NPAIRS_UP (((double)BDIM * (double)(BDIM + 1)) * 0.5)

typedef float f32x4 __attribute__((ext_vector_type(4)));
typedef int i32x8 __attribute__((ext_vector_type(8)));

// Kernel 1: per-row L2 normalize fp32 -> fp8 e4m3, coalesced; sq[row]=||n||^2; zero counter.
__global__ __launch_bounds__(256) void normalize_rows(
    const float* __restrict__ x, unsigned char* __restrict__ nf8,
    float* __restrict__ sq, unsigned int* __restrict__ counter)
{
    if (blockIdx.x == 0 && threadIdx.x == 0) { *counter = 0u; }
    int row = blockIdx.x * 4 + (threadIdx.x >> 6);
    int l = threadIdx.x & 63;
    const float4* xr = (const float4*)(x + (size_t)row * DDIM);
    float4 f0 = xr[l];
    float4 f1 = xr[l + 64];
    float s = f0.x*f0.x + f0.y*f0.y + f0.z*f0.z + f0.w*f0.w
            + f1.x*f1.x + f1.y*f1.y + f1.z*f1.z + f1.w*f1.w;
    #pragma unroll
    for (int m = 1; m < 64; m <<= 1) s += __shfl_xor(s, m);
    float rn = rsqrtf(s);
    int pk0 = __builtin_amdgcn_cvt_pk_fp8_f32(f0.x * rn, f0.y * rn, 0, false);
    pk0     = __builtin_amdgcn_cvt_pk_fp8_f32(f0.z * rn, f0.w * rn, pk0, true);
    int pk1 = __builtin_amdgcn_cvt_pk_fp8_f32(f1.x * rn, f1.y * rn, 0, false);
    pk1     = __builtin_amdgcn_cvt_pk_fp8_f32(f1.z * rn, f1.w * rn, pk1, true);
    int* rowp = (int*)(nf8 + (size_t)row * DDIM);
    rowp[l] = pk0;
    rowp[l + 64] = pk1;
    if (l == 0) sq[row] = s * rn * rn;
}

// Kernel 2: one 64x64 output tile PER WAVE, fully independent. No LDS staging,
// no barriers in the compute path. K-loop is NOT unrolled (#pragma unroll 1)
// so operand loads cannot be hoisted across iterations -- round 1's full
// unroll let the scheduler pull all 32 frag loads (256 VGPRs) above the
// MFMAs, blowing the (256,3) cap and spilling acc to scratch (353 MB of
// WRITE_SIZE). Per iteration we hold bf[4] (32 VGPRs) and stream A one
// 8-VGPR fragment at a time: peak live ~140 < 168 cap.
__global__ __launch_bounds__(256, 3) void gram_hinge(
    const unsigned char* __restrict__ nf8, const float* __restrict__ sq,
    const int* __restrict__ y, double* __restrict__ part,
    unsigned int* __restrict__ counter, float* __restrict__ out)
{
    __shared__ float wpart[4];
    __shared__ double dpart[4];
    __shared__ int is_last;

    int tid = threadIdx.x;
    int w = tid >> 6, l = tid & 63;
    int lr = l & 15, q = l >> 4;

    // ---- per-wave tile decode: u = tj*(tj+1)/2 + ti, ti<=tj (row-tile ti, col-tile tj)
    int u = blockIdx.x * 4 + w;
    int tj = (int)((sqrtf(8.0f * (float)u + 1.0f) - 1.0f) * 0.5f);
    while ((tj + 1) * (tj + 2) / 2 <= u) ++tj;
    while (tj * (tj + 1) / 2 > u) --tj;
    int ti = u - tj * (tj + 1) / 2;

    // per-lane operand base pointers: row = tile*64 + frag*16 + lr, 32 B at k-chunk q*32
    const unsigned char* Ap = nf8 + ((size_t)(ti * 64 + lr)) * DDIM + q * 32;
    const unsigned char* Bp = nf8 + ((size_t)(tj * 64 + lr)) * DDIM + q * 32;

    f32x4 accv[4][4] = {};

    #pragma unroll 1
    for (int it = 0; it < 4; ++it) {
        i32x8 bf[4];
        #pragma unroll
        for (int ni = 0; ni < 4; ++ni)
            bf[ni] = *(const i32x8*)(Bp + (size_t)ni * 16 * DDIM);
        #pragma unroll
        for (int mi = 0; mi < 4; ++mi) {
            i32x8 a = *(const i32x8*)(Ap + (size_t)mi * 16 * DDIM);
            #pragma unroll
            for (int ni = 0; ni < 4; ++ni)
                accv[mi][ni] = __builtin_amdgcn_mfma_scale_f32_16x16x128_f8f6f4(
                    a, bf[ni], accv[mi][ni],
                    0, 0, 0, 0x7F7F7F7F, 0, 0x7F7F7F7F);
        }
        Ap += 128;
        Bp += 128;
    }

    // ---- Epilogue (C/D layout: col=lane&15 -> j, row=q*4+reg -> i) ----
    float acc0 = 0.f, acc1 = 0.f, acc2 = 0.f, acc3 = 0.f;
    int jb = tj * 64 + lr;
    float sqj[4]; int yj[4];
    #pragma unroll
    for (int ni = 0; ni < 4; ++ni) {
        sqj[ni] = sq[jb + ni * 16];
        yj[ni]  = y[jb + ni * 16];
    }
    if (ti != tj) {
        // strictly above diagonal: every element counts, no index test
        #pragma unroll
        for (int mi = 0; mi < 4; ++mi) {
            #pragma unroll
            for (int r = 0; r < 4; ++r) {
                int ia = ti * 64 + mi * 16 + q * 4 + r;
                float ci = THETA - sq[ia];
                int yi = y[ia];
                float h0 = fmaxf(fmaf(2.f, accv[mi][0][r], ci - sqj[0]), 0.f);
                acc0 += (yi == yj[0]) ? h0 : -h0;
                float h1 = fmaxf(fmaf(2.f, accv[mi][1][r], ci - sqj[1]), 0.f);
                acc1 += (yi == yj[1]) ? h1 : -h1;
                float h2 = fmaxf(fmaf(2.f, accv[mi][2][r], ci - sqj[2]), 0.f);
                acc2 += (yi == yj[2]) ? h2 : -h2;
                float h3 = fmaxf(fmaf(2.f, accv[mi][3][r], ci - sqj[3]), 0.f);
                acc3 += (yi == yj[3]) ? h3 : -h3;
            }
        }
    } else {
        // diagonal tile: count only local col >= local row
        int cl0 = lr;
        #pragma unroll
        for (int mi = 0; mi < 4; ++mi) {
            #pragma unroll
            for (int r = 0; r < 4; ++r) {
                int rl_ = mi * 16 + q * 4 + r;
                int ia = ti * 64 + rl_;
                float ci = THETA - sq[ia];
                int yi = y[ia];
                #pragma unroll
                for (int ni = 0; ni < 4; ++ni) {
                    float h = fmaxf(fmaf(2.f, accv[mi][ni][r], ci - sqj[ni]), 0.f);
                    float sh = (yi == yj[ni]) ? h : -h;
                    if (cl0 + ni * 16 >= rl_) acc0 += sh;
                }
            }
        }
    }

    float local = (acc0 + acc1) + (acc2 + acc3);
    #pragma unroll
    for (int off = 32; off > 0; off >>= 1) local += __shfl_down(local, off);
    if (l == 0) wpart[w] = local;
    __syncthreads();
    if (tid == 0) {
        double ssum = (double)wpart[0] + (double)wpart[1]
                    + (double)wpart[2] + (double)wpart[3];
        __hip_atomic_store(&part[blockIdx.x], ssum, __ATOMIC_RELEASE, __HIP_MEMORY_SCOPE_AGENT);
        unsigned int ticket = __hip_atomic_fetch_add(
            counter, 1u, __ATOMIC_ACQ_REL, __HIP_MEMORY_SCOPE_AGENT);
        is_last = (ticket == NBLK - 1) ? 1 : 0;
    }
    __syncthreads();
    if (is_last) {
        double s = 0.0;
        for (int i = tid; i < NBLK; i += 256)
            s += __hip_atomic_load(&part[i], __ATOMIC_ACQUIRE, __HIP_MEMORY_SCOPE_AGENT);
        #pragma unroll
        for (int off = 32; off > 0; off >>= 1) s += __shfl_down(s, off);
        if (l == 0) dpart[w] = s;
        __syncthreads();
        if (tid == 0) {
            // add the analytically-known XI term: XI * #upper-tri pairs
            double total = (dpart[0] + dpart[1] + dpart[2] + dpart[3])
                         + (double)XI * NPAIRS_UP;
            const double m = 1.0 / ((double)BDIM * (double)BDIM - (double)BDIM);
            out[0] = (float)(total * m);
        }
    }
}

extern "C" void kernel_launch(void* const* d_in, const int* in_sizes, int n_in,
                              void* d_out, int out_size, void* d_ws, size_t ws_size,
                              hipStream_t stream) {
    const float* x = (const float*)d_in[0];
    const int* y = (const int*)d_in[1];
    float* out = (float*)d_out;

    unsigned char* nf8 = (unsigned char*)d_ws;                          // 4 MB fp8
    char* p = (char*)d_ws + (size_t)BDIM * DDIM;
    float* sq = (float*)p;                                              // 32 KB
    unsigned int* counter = (unsigned int*)(p + (size_t)BDIM * 4);
    double* part = (double*)(p + (size_t)BDIM * 4 + 64);                // NBLK doubles

    normalize_rows<<<BDIM / 4, 256, 0, stream>>>(x, nf8, sq, counter);
    gram_hinge<<<NBLK, 256, 0, stream>>>(nf8, sq, y, part, counter, out);
}

// Round 3
// 140.562 us; speedup vs baseline: 2.4440x; 1.2897x over previous
//
#include <hip/hip_runtime.h>
#include <cstdint>
#include <cstddef>

#define THETA 1.2f
#define XI 0.3f
#define BDIM 8192
#define DDIM 512
#define NTILE 64           // 64x64 grid of 128x128 tiles
#define NUPPER 2080        // NTILE*(NTILE+1)/2 upper-triangle block-tiles
#define GRID 512           // balanced grid-stride: every block gets 4-5 tiles
// upper-triangle-with-diagonal pair count: B*(B+1)/2
#define NPAIRS_UP (((double)BDIM * (double)(BDIM + 1)) * 0.5)

typedef float f32x4 __attribute__((ext_vector_type(4)));
typedef int i32x8 __attribute__((ext_vector_type(8)));

// Kernel 1: per-row L2 normalize fp32 -> fp8 e4m3, coalesced; sq[row]=||n||^2; zero counter.
__global__ __launch_bounds__(256) void normalize_rows(
    const float* __restrict__ x, unsigned char* __restrict__ nf8,
    float* __restrict__ sq, unsigned int* __restrict__ counter)
{
    if (blockIdx.x == 0 && threadIdx.x == 0) { *counter = 0u; }
    int row = blockIdx.x * 4 + (threadIdx.x >> 6);
    int l = threadIdx.x & 63;
    const float4* xr = (const float4*)(x + (size_t)row * DDIM);
    float4 f0 = xr[l];
    float4 f1 = xr[l + 64];
    float s = f0.x*f0.x + f0.y*f0.y + f0.z*f0.z + f0.w*f0.w
            + f1.x*f1.x + f1.y*f1.y + f1.z*f1.z + f1.w*f1.w;
    #pragma unroll
    for (int m = 1; m < 64; m <<= 1) s += __shfl_xor(s, m);
    float rn = rsqrtf(s);
    int pk0 = __builtin_amdgcn_cvt_pk_fp8_f32(f0.x * rn, f0.y * rn, 0, false);
    pk0     = __builtin_amdgcn_cvt_pk_fp8_f32(f0.z * rn, f0.w * rn, pk0, true);
    int pk1 = __builtin_amdgcn_cvt_pk_fp8_f32(f1.x * rn, f1.y * rn, 0, false);
    pk1     = __builtin_amdgcn_cvt_pk_fp8_f32(f1.z * rn, f1.w * rn, pk1, true);
    int* rowp = (int*)(nf8 + (size_t)row * DDIM);
    rowp[l] = pk0;
    rowp[l + 64] = pk1;
    if (l == 0) sq[row] = s * rn * rn;
}

__device__ __forceinline__ void decode_tile(int u, int& ti, int& tj) {
    // u = tj*(tj+1)/2 + ti, ti <= tj
    int t = (int)((sqrtf(8.0f * (float)u + 1.0f) - 1.0f) * 0.5f);
    while ((t + 1) * (t + 2) / 2 <= u) ++t;
    while (t * (t + 1) / 2 > u) --t;
    tj = t;
    ti = u - t * (t + 1) / 2;
}

// Kernel 2: 128x128 block-tiles (4 waves, one 64x64 quadrant each), K staged
// in 4 chunks of 128 B through double-buffered LDS via global_load_lds
// (contiguous 1 KB DMA per instr -- round 2's direct-from-global frag loads
// were 16-row scatters that thrashed L1 and exposed full L2 latency).
// T3-minimum 2-phase pipeline: stage chunk t+1, compute chunk t, one
// barrier per chunk (barrier drain doubles as the vmcnt wait). 4 chunks/tile
// keeps buffer parity compile-time (chunk c reads buf c&1, stages (c+1)&1).
// Granule swizzle: LDS[row][g] = src[row][g ^ (row&7)] (swizzled SOURCE,
// linear dest -- rule: both-sides-or-neither) so the strided frag reads
// (ds_read_b128, 16 rows x stride-128B) spread across all banks.
__global__ __launch_bounds__(256, 2) void gram_hinge(
    const unsigned char* __restrict__ nf8, const float* __restrict__ sq,
    const int* __restrict__ y, double* __restrict__ part,
    unsigned int* __restrict__ counter, float* __restrict__ out)
{
    __shared__ unsigned char As[2][128 * 128];   // 32 KB
    __shared__ unsigned char Bs[2][128 * 128];   // 32 KB
    __shared__ float wpart[4];
    __shared__ double dpart[4];
    __shared__ int is_last;

    int tid = threadIdx.x;
    int w = tid >> 6, l = tid & 63;
    int wr = w >> 1, wc = w & 1;      // wave quadrant in 128x128 tile
    int lr = l & 15, q = l >> 4;

    // staging lane constants: each instr moves 8 rows x 128 B (1 KB)
    int srow = l >> 3;                // row within 8-row group
    int sgran = (l & 7) ^ srow;       // swizzled source granule
    // frag-read lane constant: row & 7 for all frag rows this lane touches
    int sm = lr & 7;

    // stage one chunk (128 rows x 128 B each of A and B) into buffer nb
    auto stage = [&](int nb, int pti, int ptj, int pc) {
        const unsigned char* gA = nf8
            + ((size_t)(pti * 128 + w * 32 + srow)) * DDIM + pc * 128 + sgran * 16;
        const unsigned char* gB = nf8
            + ((size_t)(ptj * 128 + w * 32 + srow)) * DDIM + pc * 128 + sgran * 16;
        unsigned char* dA = &As[nb][(w * 32) * 128];
        unsigned char* dB = &Bs[nb][(w * 32) * 128];
        #pragma unroll
        for (int i = 0; i < 4; ++i) {
            __builtin_amdgcn_global_load_lds(
                (const __attribute__((address_space(1))) void*)(gA + (size_t)i * 8 * DDIM),
                (__attribute__((address_space(3))) void*)(dA + i * 1024), 16, 0, 0);
            __builtin_amdgcn_global_load_lds(
                (const __attribute__((address_space(1))) void*)(gB + (size_t)i * 8 * DDIM),
                (__attribute__((address_space(3))) void*)(dB + i * 1024), 16, 0, 0);
        }
    };

    float acc0 = 0.f, acc1 = 0.f, acc2 = 0.f, acc3 = 0.f;

    int u = blockIdx.x;
    int ti, tj;
    decode_tile(u, ti, tj);

    // prologue: stage (tile u, chunk 0) into buffer 0
    stage(0, ti, tj, 0);
    __syncthreads();

    while (u < NUPPER) {
        int u_next = u + GRID;
        bool have_next = (u_next < NUPPER);
        int ti_n = 0, tj_n = 0;
        if (have_next) decode_tile(u_next, ti_n, tj_n);

        f32x4 accv[4][4] = {};

        #pragma unroll
        for (int c = 0; c < 4; ++c) {
            // ---- stage next chunk-job into buffer (c+1)&1 (no wait) ----
            if (c < 3)           stage((c + 1) & 1, ti, tj, c + 1);
            else if (have_next)  stage(0, ti_n, tj_n, 0);

            // ---- compute chunk c from buffer c&1 ----
            const unsigned char* Ab = (const unsigned char*)As[c & 1];
            const unsigned char* Bb = (const unsigned char*)Bs[c & 1];
            i32x8 af[4], bf[4];
            #pragma unroll
            for (int f = 0; f < 4; ++f) {
                int rA = (wr * 64 + f * 16 + lr) * 128;
                int4 a0 = *(const int4*)(Ab + rA + (((2 * q + 0) ^ sm) << 4));
                int4 a1 = *(const int4*)(Ab + rA + (((2 * q + 1) ^ sm) << 4));
                af[f][0] = a0.x; af[f][1] = a0.y; af[f][2] = a0.z; af[f][3] = a0.w;
                af[f][4] = a1.x; af[f][5] = a1.y; af[f][6] = a1.z; af[f][7] = a1.w;
                int rB = (wc * 64 + f * 16 + lr) * 128;
                int4 b0 = *(const int4*)(Bb + rB + (((2 * q + 0) ^ sm) << 4));
                int4 b1 = *(const int4*)(Bb + rB + (((2 * q + 1) ^ sm) << 4));
                bf[f][0] = b0.x; bf[f][1] = b0.y; bf[f][2] = b0.z; bf[f][3] = b0.w;
                bf[f][4] = b1.x; bf[f][5] = b1.y; bf[f][6] = b1.z; bf[f][7] = b1.w;
            }
            #pragma unroll
            for (int mi = 0; mi < 4; ++mi)
                #pragma unroll
                for (int ni = 0; ni < 4; ++ni)
                    accv[mi][ni] = __builtin_amdgcn_mfma_scale_f32_16x16x128_f8f6f4(
                        af[mi], bf[ni], accv[mi][ni],
                        0, 0, 0, 0x7F7F7F7F, 0, 0x7F7F7F7F);

            // ---- per-tile epilogue after last chunk (hides prefetch too) ----
            if (c == 3) {
                int jb = tj * 128 + wc * 64 + lr;
                float sqj[4]; int yj[4];
                #pragma unroll
                for (int ni = 0; ni < 4; ++ni) {
                    sqj[ni] = sq[jb + ni * 16];
                    yj[ni]  = y[jb + ni * 16];
                }
                bool skip = (ti == tj) && (wr > wc);        // strictly below diag
                bool full = (ti != tj) || (wc > wr);        // fully above diag
                if (!skip) {
                    if (full) {
                        #pragma unroll
                        for (int mi = 0; mi < 4; ++mi) {
                            #pragma unroll
                            for (int r = 0; r < 4; ++r) {
                                int ia = ti * 128 + wr * 64 + mi * 16 + q * 4 + r;
                                float ci = THETA - sq[ia];
                                int yi = y[ia];
                                float h0 = fmaxf(fmaf(2.f, accv[mi][0][r], ci - sqj[0]), 0.f);
                                acc0 += (yi == yj[0]) ? h0 : -h0;
                                float h1 = fmaxf(fmaf(2.f, accv[mi][1][r], ci - sqj[1]), 0.f);
                                acc1 += (yi == yj[1]) ? h1 : -h1;
                                float h2 = fmaxf(fmaf(2.f, accv[mi][2][r], ci - sqj[2]), 0.f);
                                acc2 += (yi == yj[2]) ? h2 : -h2;
                                float h3 = fmaxf(fmaf(2.f, accv[mi][3][r], ci - sqj[3]), 0.f);
                                acc3 += (yi == yj[3]) ? h3 : -h3;
                            }
                        }
                    } else {
                        // diagonal quadrant (wr==wc): count local col >= local row
                        #pragma unroll
                        for (int mi = 0; mi < 4; ++mi) {
                            #pragma unroll
                            for (int r = 0; r < 4; ++r) {
                                int rl_ = mi * 16 + q * 4 + r;
                                int ia = ti * 128 + wr * 64 + rl_;
                                float ci = THETA - sq[ia];
                                int yi = y[ia];
                                #pragma unroll
                                for (int ni = 0; ni < 4; ++ni) {
                                    float h = fmaxf(fmaf(2.f, accv[mi][ni][r], ci - sqj[ni]), 0.f);
                                    float sh = (yi == yj[ni]) ? h : -h;
                                    if (ni * 16 + lr >= rl_) acc0 += sh;
                                }
                            }
                        }
                    }
                }
            }
            __syncthreads();   // drains vmcnt (prefetch landed) + lgkmcnt
        }
        u = u_next; ti = ti_n; tj = tj_n;
    }

    float local = (acc0 + acc1) + (acc2 + acc3);
    #pragma unroll
    for (int off = 32; off > 0; off >>= 1) local += __shfl_down(local, off);
    if (l == 0) wpart[w] = local;
    __syncthreads();
    if (tid == 0) {
        double ssum = (double)wpart[0] + (double)wpart[1]
                    + (double)wpart[2] + (double)wpart[3];
        __hip_atomic_store(&part[blockIdx.x], ssum, __ATOMIC_RELEASE, __HIP_MEMORY_SCOPE_AGENT);
        unsigned int ticket = __hip_atomic_fetch_add(
            counter, 1u, __ATOMIC_ACQ_REL, __HIP_MEMORY_SCOPE_AGENT);
        is_last = (ticket == GRID - 1) ? 1 : 0;
    }
    __syncthreads();
    if (is_last) {
        double s = 0.0;
        for (int i = tid; i < GRID; i += 256)
            s += __hip_atomic_load(&part[i], __ATOMIC_ACQUIRE, __HIP_MEMORY_SCOPE_AGENT);
        #pragma unroll
        for (int off = 32; off > 0; off >>= 1) s += __shfl_down(s, off);
        if (l == 0) dpart[w] = s;
        __syncthreads();
        if (tid == 0) {
            // add the analytically-known XI term: XI * #upper-tri pairs
            double total = (dpart[0] + dpart[1] + dpart[2] + dpart[3])
                         + (double)XI * NPAIRS_UP;
            const double m = 1.0 / ((double)BDIM * (double)BDIM - (double)BDIM);
            out[0] = (float)(total * m);
        }
    }
}

extern "C" void kernel_launch(void* const* d_in, const int* in_sizes, int n_in,
                              void* d_out, int out_size, void* d_ws, size_t ws_size,
                              hipStream_t stream) {
    const float* x = (const float*)d_in[0];
    const int* y = (const int*)d_in[1];
    float* out = (float*)d_out;

    unsigned char* nf8 = (unsigned char*)d_ws;                          // 4 MB fp8
    char* p = (char*)d_ws + (size_t)BDIM * DDIM;
    float* sq = (float*)p;                                              // 32 KB
    unsigned int* counter = (unsigned int*)(p + (size_t)BDIM * 4);
    double* part = (double*)(p + (size_t)BDIM * 4 + 64);                // GRID doubles

    normalize_rows<<<BDIM / 4, 256, 0, stream>>>(x, nf8, sq, counter);
    gram_hinge<<<GRID, 256, 0, stream>>>(nf8, sq, y, part, counter, out);
}

// Round 4
// 105.919 us; speedup vs baseline: 3.2434x; 1.3271x over previous
//
#include <hip/hip_runtime.h>
#include <cstdint>
#include <cstddef>

#define THETA 1.2f
#define XI 0.3f
#define BDIM 8192
#define DDIM 512
#define NTILE 64           // 64x64 grid of 128x128 tiles
#define NUPPER 2080        // NTILE*(NTILE+1)/2 upper-triangle block-tiles
#define GRID 512           // balanced grid-stride: every block gets 4-5 tiles
// upper-triangle-with-diagonal pair count: B*(B+1)/2
#define NPAIRS_UP (((double)BDIM * (double)(BDIM + 1)) * 0.5)

typedef float f32x4 __attribute__((ext_vector_type(4)));
typedef int i32x8 __attribute__((ext_vector_type(8)));

// Kernel 1: per-row L2 normalize fp32 -> fp8 e4m3, coalesced; sq[row]=||n||^2; zero counter.
__global__ __launch_bounds__(256) void normalize_rows(
    const float* __restrict__ x, unsigned char* __restrict__ nf8,
    float* __restrict__ sq, unsigned int* __restrict__ counter)
{
    if (blockIdx.x == 0 && threadIdx.x == 0) { *counter = 0u; }
    int row = blockIdx.x * 4 + (threadIdx.x >> 6);
    int l = threadIdx.x & 63;
    const float4* xr = (const float4*)(x + (size_t)row * DDIM);
    float4 f0 = xr[l];
    float4 f1 = xr[l + 64];
    float s = f0.x*f0.x + f0.y*f0.y + f0.z*f0.z + f0.w*f0.w
            + f1.x*f1.x + f1.y*f1.y + f1.z*f1.z + f1.w*f1.w;
    #pragma unroll
    for (int m = 1; m < 64; m <<= 1) s += __shfl_xor(s, m);
    float rn = rsqrtf(s);
    int pk0 = __builtin_amdgcn_cvt_pk_fp8_f32(f0.x * rn, f0.y * rn, 0, false);
    pk0     = __builtin_amdgcn_cvt_pk_fp8_f32(f0.z * rn, f0.w * rn, pk0, true);
    int pk1 = __builtin_amdgcn_cvt_pk_fp8_f32(f1.x * rn, f1.y * rn, 0, false);
    pk1     = __builtin_amdgcn_cvt_pk_fp8_f32(f1.z * rn, f1.w * rn, pk1, true);
    int* rowp = (int*)(nf8 + (size_t)row * DDIM);
    rowp[l] = pk0;
    rowp[l + 64] = pk1;
    if (l == 0) sq[row] = s * rn * rn;
}

__device__ __forceinline__ void decode_tile(int u, int& ti, int& tj) {
    // u = tj*(tj+1)/2 + ti, ti <= tj
    int t = (int)((sqrtf(8.0f * (float)u + 1.0f) - 1.0f) * 0.5f);
    while ((t + 1) * (t + 2) / 2 <= u) ++t;
    while (t * (t + 1) / 2 > u) --t;
    tj = t;
    ti = u - t * (t + 1) / 2;
}

// Kernel 2: 128x128 block-tiles (4 waves x one 64x64 quadrant), K in 4 chunks
// of 128 B via double-buffered LDS (global_load_lds, 1 KB DMA per instr),
// granule-swizzled source / linear dest / swizzled read.
// Round-4 change vs round 3: the chunk loop is NOT unrolled (#pragma unroll 1)
// so each per-chunk __syncthreads is a hard register-live-range fence; A
// fragments are streamed one at a time (bf[4]=32 + af=8 regs instead of 64);
// the epilogue is outside the chunk loop. Round 3's unrolled loop + embedded
// epilogue merged all live ranges -> scratch spill (82 MB WRITE_SIZE = the
// whole 81 us). Peak live now ~140 VGPR < 256 cap: no spill by construction.
__global__ __launch_bounds__(256, 2) void gram_hinge(
    const unsigned char* __restrict__ nf8, const float* __restrict__ sq,
    const int* __restrict__ y, double* __restrict__ part,
    unsigned int* __restrict__ counter, float* __restrict__ out)
{
    __shared__ unsigned char As[2][128 * 128];   // 32 KB
    __shared__ unsigned char Bs[2][128 * 128];   // 32 KB
    __shared__ float wpart[4];
    __shared__ double dpart[4];
    __shared__ int is_last;

    int tid = threadIdx.x;
    int w = tid >> 6, l = tid & 63;
    int wr = w >> 1, wc = w & 1;      // wave quadrant in 128x128 tile
    int lr = l & 15, q = l >> 4;

    // staging lane constants: each instr moves 8 rows x 128 B (1 KB)
    int srow = l >> 3;                // row within 8-row group
    int sgran = (l & 7) ^ srow;       // swizzled source granule
    int sm = lr & 7;                  // read-side swizzle key (= frag row & 7)

    // stage one 128-row x 128-B chunk of A and B into given LDS buffers
    auto stage = [&](unsigned char* dAb, unsigned char* dBb, int pti, int ptj, int pc) {
        const unsigned char* gA = nf8
            + ((size_t)(pti * 128 + w * 32 + srow)) * DDIM + pc * 128 + sgran * 16;
        const unsigned char* gB = nf8
            + ((size_t)(ptj * 128 + w * 32 + srow)) * DDIM + pc * 128 + sgran * 16;
        unsigned char* dA = dAb + (w * 32) * 128;
        unsigned char* dB = dBb + (w * 32) * 128;
        #pragma unroll
        for (int i = 0; i < 4; ++i) {
            __builtin_amdgcn_global_load_lds(
                (const __attribute__((address_space(1))) void*)(gA + (size_t)i * 8 * DDIM),
                (__attribute__((address_space(3))) void*)(dA + i * 1024), 16, 0, 0);
            __builtin_amdgcn_global_load_lds(
                (const __attribute__((address_space(1))) void*)(gB + (size_t)i * 8 * DDIM),
                (__attribute__((address_space(3))) void*)(dB + i * 1024), 16, 0, 0);
        }
    };

    float acc0 = 0.f, acc1 = 0.f, acc2 = 0.f, acc3 = 0.f;

    int u = blockIdx.x;
    int ti, tj;
    decode_tile(u, ti, tj);

    // prologue: stage (tile u, chunk 0) into buffer 0
    stage(As[0], Bs[0], ti, tj, 0);
    __syncthreads();

    while (u < NUPPER) {
        int u_next = u + GRID;
        bool have_next = (u_next < NUPPER);
        int ti_n = 0, tj_n = 0;
        if (have_next) decode_tile(u_next, ti_n, tj_n);

        f32x4 accv[4][4] = {};

        #pragma unroll 1
        for (int c = 0; c < 4; ++c) {
            // ---- issue next chunk-job into buffer (c+1)&1 (no wait) ----
            if (c < 3) {
                stage(As[(c + 1) & 1], Bs[(c + 1) & 1], ti, tj, c + 1);
            } else if (have_next) {
                stage(As[0], Bs[0], ti_n, tj_n, 0);
            }

            // ---- compute chunk c from buffer c&1 ----
            const unsigned char* Ab = As[c & 1];
            const unsigned char* Bb = Bs[c & 1];
            i32x8 bf[4];
            #pragma unroll
            for (int f = 0; f < 4; ++f) {
                int rB = (wc * 64 + f * 16 + lr) * 128;
                int4 b0 = *(const int4*)(Bb + rB + (((2 * q + 0) ^ sm) << 4));
                int4 b1 = *(const int4*)(Bb + rB + (((2 * q + 1) ^ sm) << 4));
                bf[f][0] = b0.x; bf[f][1] = b0.y; bf[f][2] = b0.z; bf[f][3] = b0.w;
                bf[f][4] = b1.x; bf[f][5] = b1.y; bf[f][6] = b1.z; bf[f][7] = b1.w;
            }
            #pragma unroll
            for (int mi = 0; mi < 4; ++mi) {
                int rA = (wr * 64 + mi * 16 + lr) * 128;
                int4 a0 = *(const int4*)(Ab + rA + (((2 * q + 0) ^ sm) << 4));
                int4 a1 = *(const int4*)(Ab + rA + (((2 * q + 1) ^ sm) << 4));
                i32x8 af;
                af[0] = a0.x; af[1] = a0.y; af[2] = a0.z; af[3] = a0.w;
                af[4] = a1.x; af[5] = a1.y; af[6] = a1.z; af[7] = a1.w;
                #pragma unroll
                for (int ni = 0; ni < 4; ++ni)
                    accv[mi][ni] = __builtin_amdgcn_mfma_scale_f32_16x16x128_f8f6f4(
                        af, bf[ni], accv[mi][ni],
                        0, 0, 0, 0x7F7F7F7F, 0, 0x7F7F7F7F);
            }

            __syncthreads();   // drains vmcnt (prefetch landed) + lgkmcnt; fences regs
        }

        // ---- per-tile epilogue (accv only live state besides acc0..3) ----
        {
            int jb = tj * 128 + wc * 64 + lr;
            float sqj[4]; int yj[4];
            #pragma unroll
            for (int ni = 0; ni < 4; ++ni) {
                sqj[ni] = sq[jb + ni * 16];
                yj[ni]  = y[jb + ni * 16];
            }
            bool skip = (ti == tj) && (wr > wc);        // strictly below diag
            bool full = (ti != tj) || (wc > wr);        // fully above diag
            if (!skip) {
                if (full) {
                    #pragma unroll
                    for (int mi = 0; mi < 4; ++mi) {
                        #pragma unroll
                        for (int r = 0; r < 4; ++r) {
                            int ia = ti * 128 + wr * 64 + mi * 16 + q * 4 + r;
                            float ci = THETA - sq[ia];
                            int yi = y[ia];
                            float h0 = fmaxf(fmaf(2.f, accv[mi][0][r], ci - sqj[0]), 0.f);
                            acc0 += (yi == yj[0]) ? h0 : -h0;
                            float h1 = fmaxf(fmaf(2.f, accv[mi][1][r], ci - sqj[1]), 0.f);
                            acc1 += (yi == yj[1]) ? h1 : -h1;
                            float h2 = fmaxf(fmaf(2.f, accv[mi][2][r], ci - sqj[2]), 0.f);
                            acc2 += (yi == yj[2]) ? h2 : -h2;
                            float h3 = fmaxf(fmaf(2.f, accv[mi][3][r], ci - sqj[3]), 0.f);
                            acc3 += (yi == yj[3]) ? h3 : -h3;
                        }
                    }
                } else {
                    // diagonal quadrant (wr==wc): count local col >= local row
                    #pragma unroll
                    for (int mi = 0; mi < 4; ++mi) {
                        #pragma unroll
                        for (int r = 0; r < 4; ++r) {
                            int rl_ = mi * 16 + q * 4 + r;
                            int ia = ti * 128 + wr * 64 + rl_;
                            float ci = THETA - sq[ia];
                            int yi = y[ia];
                            #pragma unroll
                            for (int ni = 0; ni < 4; ++ni) {
                                float h = fmaxf(fmaf(2.f, accv[mi][ni][r], ci - sqj[ni]), 0.f);
                                float sh = (yi == yj[ni]) ? h : -h;
                                if (ni * 16 + lr >= rl_) acc0 += sh;
                            }
                        }
                    }
                }
            }
        }

        u = u_next; ti = ti_n; tj = tj_n;
    }

    float local = (acc0 + acc1) + (acc2 + acc3);
    #pragma unroll
    for (int off = 32; off > 0; off >>= 1) local += __shfl_down(local, off);
    if (l == 0) wpart[w] = local;
    __syncthreads();
    if (tid == 0) {
        double ssum = (double)wpart[0] + (double)wpart[1]
                    + (double)wpart[2] + (double)wpart[3];
        __hip_atomic_store(&part[blockIdx.x], ssum, __ATOMIC_RELEASE, __HIP_MEMORY_SCOPE_AGENT);
        unsigned int ticket = __hip_atomic_fetch_add(
            counter, 1u, __ATOMIC_ACQ_REL, __HIP_MEMORY_SCOPE_AGENT);
        is_last = (ticket == GRID - 1) ? 1 : 0;
    }
    __syncthreads();
    if (is_last) {
        double s = 0.0;
        for (int i = tid; i < GRID; i += 256)
            s += __hip_atomic_load(&part[i], __ATOMIC_ACQUIRE, __HIP_MEMORY_SCOPE_AGENT);
        #pragma unroll
        for (int off = 32; off > 0; off >>= 1) s += __shfl_down(s, off);
        if (l == 0) dpart[w] = s;
        __syncthreads();
        if (tid == 0) {
            // add the analytically-known XI term: XI * #upper-tri pairs
            double total = (dpart[0] + dpart[1] + dpart[2] + dpart[3])
                         + (double)XI * NPAIRS_UP;
            const double m = 1.0 / ((double)BDIM * (double)BDIM - (double)BDIM);
            out[0] = (float)(total * m);
        }
    }
}

extern "C" void kernel_launch(void* const* d_in, const int* in_sizes, int n_in,
                              void* d_out, int out_size, void* d_ws, size_t ws_size,
                              hipStream_t stream) {
    const float* x = (const float*)d_in[0];
    const int* y = (const int*)d_in[1];
    float* out = (float*)d_out;

    unsigned char* nf8 = (unsigned char*)d_ws;                          // 4 MB fp8
    char* p = (char*)d_ws + (size_t)BDIM * DDIM;
    float* sq = (float*)p;                                              // 32 KB
    unsigned int* counter = (unsigned int*)(p + (size_t)BDIM * 4);
    double* part = (double*)(p + (size_t)BDIM * 4 + 64);                // GRID doubles

    normalize_rows<<<BDIM / 4, 256, 0, stream>>>(x, nf8, sq, counter);
    gram_hinge<<<GRID, 256, 0, stream>>>(nf8, sq, y, part, counter, out);
}

// Round 5
// 103.408 us; speedup vs baseline: 3.3221x; 1.0243x over previous
//
#include <hip/hip_runtime.h>
#include <cstdint>
#include <cstddef>

#define THETA 1.2f
#define XI 0.3f
#define BDIM 8192
#define DDIM 512
#define NTILE 64           // 64x64 grid of 128x128 tiles
#define NUPPER 2080        // NTILE*(NTILE+1)/2 upper-triangle block-tiles
#define GRID 512           // balanced grid-stride: every block gets 4-5 tiles
// upper-triangle-with-diagonal pair count: B*(B+1)/2
#define NPAIRS_UP (((double)BDIM * (double)(BDIM + 1)) * 0.5)

typedef float f32x4 __attribute__((ext_vector_type(4)));
typedef int i32x8 __attribute__((ext_vector_type(8)));

// Kernel 1: per-row L2 normalize fp32 -> fp8 e4m3, coalesced; sq[row]=||n||^2; zero counter.
__global__ __launch_bounds__(256) void normalize_rows(
    const float* __restrict__ x, unsigned char* __restrict__ nf8,
    float* __restrict__ sq, unsigned int* __restrict__ counter)
{
    if (blockIdx.x == 0 && threadIdx.x == 0) { *counter = 0u; }
    int row = blockIdx.x * 4 + (threadIdx.x >> 6);
    int l = threadIdx.x & 63;
    const float4* xr = (const float4*)(x + (size_t)row * DDIM);
    float4 f0 = xr[l];
    float4 f1 = xr[l + 64];
    float s = f0.x*f0.x + f0.y*f0.y + f0.z*f0.z + f0.w*f0.w
            + f1.x*f1.x + f1.y*f1.y + f1.z*f1.z + f1.w*f1.w;
    #pragma unroll
    for (int m = 1; m < 64; m <<= 1) s += __shfl_xor(s, m);
    float rn = rsqrtf(s);
    int pk0 = __builtin_amdgcn_cvt_pk_fp8_f32(f0.x * rn, f0.y * rn, 0, false);
    pk0     = __builtin_amdgcn_cvt_pk_fp8_f32(f0.z * rn, f0.w * rn, pk0, true);
    int pk1 = __builtin_amdgcn_cvt_pk_fp8_f32(f1.x * rn, f1.y * rn, 0, false);
    pk1     = __builtin_amdgcn_cvt_pk_fp8_f32(f1.z * rn, f1.w * rn, pk1, true);
    int* rowp = (int*)(nf8 + (size_t)row * DDIM);
    rowp[l] = pk0;
    rowp[l + 64] = pk1;
    if (l == 0) sq[row] = s * rn * rn;
}

__device__ __forceinline__ void decode_tile(int u, int& ti, int& tj) {
    // u = tj*(tj+1)/2 + ti, ti <= tj
    int t = (int)((sqrtf(8.0f * (float)u + 1.0f) - 1.0f) * 0.5f);
    while ((t + 1) * (t + 2) / 2 <= u) ++t;
    while (t * (t + 1) / 2 > u) --t;
    tj = t;
    ti = u - t * (t + 1) / 2;
}

// Kernel 2: 128x128 block-tiles, double-buffered LDS via global_load_lds.
// Round-5 change: counted-vmcnt two-barrier schedule (T4) replaces the
// per-chunk __syncthreads drain0 (round 4's __syncthreads lowered to
// s_waitcnt vmcnt(0) -- draining the just-issued prefetch every chunk,
// the m233-measured ~72% 2-phase overhead). Per chunk:
//   issue stage(c+1)            [8 DMA, stays in flight across barriers]
//   s_waitcnt vmcnt(8)          [own stage(c) landed]
//   s_barrier                   [ALL waves' stage(c) landed -> reads safe]
//   ds_read + MFMA (setprio 1)
//   s_barrier                   [all reads done before anyone's next overwrite]
// Hazards: DMA into buf[(c+1)&1] is separated from its last readers
// (chunk c-1) by chunk c-1's barrier #2; ds_read of buf[c&1] follows every
// wave's vmcnt-verify + barrier #1. Barriers are inline asm with "memory"
// clobber so ds_reads can't be hoisted/sunk across them.
__global__ __launch_bounds__(256, 2) void gram_hinge(
    const unsigned char* __restrict__ nf8, const float* __restrict__ sq,
    const int* __restrict__ y, double* __restrict__ part,
    unsigned int* __restrict__ counter, float* __restrict__ out)
{
    __shared__ unsigned char As[2][128 * 128];   // 32 KB
    __shared__ unsigned char Bs[2][128 * 128];   // 32 KB
    __shared__ float wpart[4];
    __shared__ double dpart[4];
    __shared__ int is_last;

    int tid = threadIdx.x;
    int w = tid >> 6, l = tid & 63;
    int wr = w >> 1, wc = w & 1;      // wave quadrant in 128x128 tile
    int lr = l & 15, q = l >> 4;

    // staging lane constants: each instr moves 8 rows x 128 B (1 KB)
    int srow = l >> 3;                // row within 8-row group
    int sgran = (l & 7) ^ srow;       // swizzled source granule
    int sm = lr & 7;                  // read-side swizzle key (= frag row & 7)

    // stage one 128-row x 128-B chunk of A and B into given LDS buffers
    auto stage = [&](unsigned char* dAb, unsigned char* dBb, int pti, int ptj, int pc) {
        const unsigned char* gA = nf8
            + ((size_t)(pti * 128 + w * 32 + srow)) * DDIM + pc * 128 + sgran * 16;
        const unsigned char* gB = nf8
            + ((size_t)(ptj * 128 + w * 32 + srow)) * DDIM + pc * 128 + sgran * 16;
        unsigned char* dA = dAb + (w * 32) * 128;
        unsigned char* dB = dBb + (w * 32) * 128;
        #pragma unroll
        for (int i = 0; i < 4; ++i) {
            __builtin_amdgcn_global_load_lds(
                (const __attribute__((address_space(1))) void*)(gA + (size_t)i * 8 * DDIM),
                (__attribute__((address_space(3))) void*)(dA + i * 1024), 16, 0, 0);
            __builtin_amdgcn_global_load_lds(
                (const __attribute__((address_space(1))) void*)(gB + (size_t)i * 8 * DDIM),
                (__attribute__((address_space(3))) void*)(dB + i * 1024), 16, 0, 0);
        }
    };

    float acc0 = 0.f, acc1 = 0.f, acc2 = 0.f, acc3 = 0.f;

    int u = blockIdx.x;
    int ti, tj;
    decode_tile(u, ti, tj);

    // prologue: stage (tile u, chunk 0) into buffer 0 (verified at first vmcnt)
    stage(As[0], Bs[0], ti, tj, 0);

    while (u < NUPPER) {
        int u_next = u + GRID;
        bool have_next = (u_next < NUPPER);
        int ti_n = 0, tj_n = 0;
        if (have_next) decode_tile(u_next, ti_n, tj_n);

        f32x4 accv[4][4] = {};

        #pragma unroll 1
        for (int c = 0; c < 4; ++c) {
            // ---- issue next chunk-job (stays in flight across both barriers) ----
            if (c < 3) {
                stage(As[(c + 1) & 1], Bs[(c + 1) & 1], ti, tj, c + 1);
                asm volatile("s_waitcnt vmcnt(8)" ::: "memory");   // own stage(c) landed
            } else if (have_next) {
                stage(As[0], Bs[0], ti_n, tj_n, 0);
                asm volatile("s_waitcnt vmcnt(8)" ::: "memory");   // own stage(c) landed
            } else {
                asm volatile("s_waitcnt vmcnt(0)" ::: "memory");   // nothing newer: drain
            }
            asm volatile("s_barrier" ::: "memory");                // all stage(c) landed

            // ---- compute chunk c from buffer c&1 ----
            const unsigned char* Ab = As[c & 1];
            const unsigned char* Bb = Bs[c & 1];
            i32x8 bf[4];
            #pragma unroll
            for (int f = 0; f < 4; ++f) {
                int rB = (wc * 64 + f * 16 + lr) * 128;
                int4 b0 = *(const int4*)(Bb + rB + (((2 * q + 0) ^ sm) << 4));
                int4 b1 = *(const int4*)(Bb + rB + (((2 * q + 1) ^ sm) << 4));
                bf[f][0] = b0.x; bf[f][1] = b0.y; bf[f][2] = b0.z; bf[f][3] = b0.w;
                bf[f][4] = b1.x; bf[f][5] = b1.y; bf[f][6] = b1.z; bf[f][7] = b1.w;
            }
            __builtin_amdgcn_s_setprio(1);
            #pragma unroll
            for (int mi = 0; mi < 4; ++mi) {
                int rA = (wr * 64 + mi * 16 + lr) * 128;
                int4 a0 = *(const int4*)(Ab + rA + (((2 * q + 0) ^ sm) << 4));
                int4 a1 = *(const int4*)(Ab + rA + (((2 * q + 1) ^ sm) << 4));
                i32x8 af;
                af[0] = a0.x; af[1] = a0.y; af[2] = a0.z; af[3] = a0.w;
                af[4] = a1.x; af[5] = a1.y; af[6] = a1.z; af[7] = a1.w;
                #pragma unroll
                for (int ni = 0; ni < 4; ++ni)
                    accv[mi][ni] = __builtin_amdgcn_mfma_scale_f32_16x16x128_f8f6f4(
                        af, bf[ni], accv[mi][ni],
                        0, 0, 0, 0x7F7F7F7F, 0, 0x7F7F7F7F);
            }
            __builtin_amdgcn_s_setprio(0);

            // all waves' reads of buf[c&1] done before next chunk's DMA overwrite
            asm volatile("s_barrier" ::: "memory");
        }

        // ---- per-tile epilogue (accv only live state besides acc0..3) ----
        {
            int jb = tj * 128 + wc * 64 + lr;
            float sqj[4]; int yj[4];
            #pragma unroll
            for (int ni = 0; ni < 4; ++ni) {
                sqj[ni] = sq[jb + ni * 16];
                yj[ni]  = y[jb + ni * 16];
            }
            bool skip = (ti == tj) && (wr > wc);        // strictly below diag
            bool full = (ti != tj) || (wc > wr);        // fully above diag
            if (!skip) {
                if (full) {
                    #pragma unroll
                    for (int mi = 0; mi < 4; ++mi) {
                        #pragma unroll
                        for (int r = 0; r < 4; ++r) {
                            int ia = ti * 128 + wr * 64 + mi * 16 + q * 4 + r;
                            float ci = THETA - sq[ia];
                            int yi = y[ia];
                            float h0 = fmaxf(fmaf(2.f, accv[mi][0][r], ci - sqj[0]), 0.f);
                            acc0 += (yi == yj[0]) ? h0 : -h0;
                            float h1 = fmaxf(fmaf(2.f, accv[mi][1][r], ci - sqj[1]), 0.f);
                            acc1 += (yi == yj[1]) ? h1 : -h1;
                            float h2 = fmaxf(fmaf(2.f, accv[mi][2][r], ci - sqj[2]), 0.f);
                            acc2 += (yi == yj[2]) ? h2 : -h2;
                            float h3 = fmaxf(fmaf(2.f, accv[mi][3][r], ci - sqj[3]), 0.f);
                            acc3 += (yi == yj[3]) ? h3 : -h3;
                        }
                    }
                } else {
                    // diagonal quadrant (wr==wc): count local col >= local row
                    #pragma unroll
                    for (int mi = 0; mi < 4; ++mi) {
                        #pragma unroll
                        for (int r = 0; r < 4; ++r) {
                            int rl_ = mi * 16 + q * 4 + r;
                            int ia = ti * 128 + wr * 64 + rl_;
                            float ci = THETA - sq[ia];
                            int yi = y[ia];
                            #pragma unroll
                            for (int ni = 0; ni < 4; ++ni) {
                                float h = fmaxf(fmaf(2.f, accv[mi][ni][r], ci - sqj[ni]), 0.f);
                                float sh = (yi == yj[ni]) ? h : -h;
                                if (ni * 16 + lr >= rl_) acc0 += sh;
                            }
                        }
                    }
                }
            }
        }

        u = u_next; ti = ti_n; tj = tj_n;
    }

    float local = (acc0 + acc1) + (acc2 + acc3);
    #pragma unroll
    for (int off = 32; off > 0; off >>= 1) local += __shfl_down(local, off);
    if (l == 0) wpart[w] = local;
    __syncthreads();
    if (tid == 0) {
        double ssum = (double)wpart[0] + (double)wpart[1]
                    + (double)wpart[2] + (double)wpart[3];
        __hip_atomic_store(&part[blockIdx.x], ssum, __ATOMIC_RELEASE, __HIP_MEMORY_SCOPE_AGENT);
        unsigned int ticket = __hip_atomic_fetch_add(
            counter, 1u, __ATOMIC_ACQ_REL, __HIP_MEMORY_SCOPE_AGENT);
        is_last = (ticket == GRID - 1) ? 1 : 0;
    }
    __syncthreads();
    if (is_last) {
        double s = 0.0;
        for (int i = tid; i < GRID; i += 256)
            s += __hip_atomic_load(&part[i], __ATOMIC_ACQUIRE, __HIP_MEMORY_SCOPE_AGENT);
        #pragma unroll
        for (int off = 32; off > 0; off >>= 1) s += __shfl_down(s, off);
        if (l == 0) dpart[w] = s;
        __syncthreads();
        if (tid == 0) {
            // add the analytically-known XI term: XI * #upper-tri pairs
            double total = (dpart[0] + dpart[1] + dpart[2] + dpart[3])
                         + (double)XI * NPAIRS_UP;
            const double m = 1.0 / ((double)BDIM * (double)BDIM - (double)BDIM);
            out[0] = (float)(total * m);
        }
    }
}

extern "C" void kernel_launch(void* const* d_in, const int* in_sizes, int n_in,
                              void* d_out, int out_size, void* d_ws, size_t ws_size,
                              hipStream_t stream) {
    const float* x = (const float*)d_in[0];
    const int* y = (const int*)d_in[1];
    float* out = (float*)d_out;

    unsigned char* nf8 = (unsigned char*)d_ws;                          // 4 MB fp8
    char* p = (char*)d_ws + (size_t)BDIM * DDIM;
    float* sq = (float*)p;                                              // 32 KB
    unsigned int* counter = (unsigned int*)(p + (size_t)BDIM * 4);
    double* part = (double*)(p + (size_t)BDIM * 4 + 64);                // GRID doubles

    normalize_rows<<<BDIM / 4, 256, 0, stream>>>(x, nf8, sq, counter);
    gram_hinge<<<GRID, 256, 0, stream>>>(nf8, sq, y, part, counter, out);
}